// Round 10
// baseline (101.352 us; speedup 1.0000x reference)
//
#include <hip/hip_runtime.h>

// ConvCapsuleLayer: B=2, 48x48, IN_CAPS=8, ATOMS=16, KER=3, OUT_CAPS=16, R=3.
// One 256-thread block per pixel (N=4232). Thread t=(o=t>>4, a=(t>>2)&3, c=t&3).
// Round-10: w_s DELETED (-8KB LDS -> 25.7KB -> 6 blocks/CU, was 4).
//  - wreg loaded directly from global W (identical across blocks, L1-cached).
//  - G build computed from wreg via quad-DPP butterflies (v is lane-local):
//      y_b = wreg[ic][b]*v;  quad_sum_{c'}(y_b) = G[ic,o,a,b]; select b=c.
//    No W rows in LDS, no wreg2 (round-8 spiller), nothing new persistent.

#define IN_CAPS 8
#define OUT_CAPS 16
#define KK 9
#define KKIN 72
#define BATCH 2
#define H_IN 48
#define W_IN 48
#define HO 46
#define WO 46
#define CIN 136
#define NPIX (BATCH*HO*WO)   // 4232

template<int CTRL>
__device__ __forceinline__ float dpp_f(float x) {
    return __int_as_float(
        __builtin_amdgcn_update_dpp(0, __float_as_int(x), CTRL, 0xF, 0xF, true));
}
// sum across the 16 lanes of a DPP row (the e-group): 4 pure-VALU adds
__device__ __forceinline__ float row_sum16(float x) {
    x += dpp_f<0xB1>(x);    // quad_perm xor1
    x += dpp_f<0x4E>(x);    // quad_perm xor2
    x += dpp_f<0x124>(x);   // row_ror:4
    x += dpp_f<0x128>(x);   // row_ror:8
    return x;
}
// full sum within a quad (both butterflies), result in all 4 lanes
__device__ __forceinline__ float quad_sum4(float x) {
    x += dpp_f<0xB1>(x);    // xor1
    x += dpp_f<0x4E>(x);    // xor2
    return x;
}

// pose_s row start: stride 20 + skew in {0,4}; max skew delta -4 <= pad -> no
// overlap; splits the 4-way (k,k+8,k+16,k+24) bank group into 2-way (free).
__device__ __forceinline__ int pose_row(int k) {
    return k * 20 + ((k >> 3) & 1) * 4;
}
// G row start for (o, ic): stride 20 rows + 4*o skew -> fused-phase reads hit
// 8 distinct bank groups (2 addresses each = free); write is <=4-way.
__device__ __forceinline__ int g_row(int o, int ic) {
    return (o * 8 + ic) * 20 + o * 4;
}

__global__ __launch_bounds__(256, 4)
void capsule_routing_kernel(const float* __restrict__ x,
                            const float* __restrict__ Wg,
                            float* __restrict__ out)
{
    __shared__ alignas(16) float pose_s[1440];             // skewed [k][atom] 5760 B
    __shared__ alignas(16) float pose_t[16 * 76];          // [a*4+b][k]      4864 B
    __shared__ float act_s[KKIN];                          //                  288 B
    __shared__ alignas(16) float g_s[2620];                // G              10480 B
    __shared__ alignas(16) float coup_s[OUT_CAPS * 76];    // [o][k]          4864 B
    // total ~25.7 KB -> 6 blocks/CU

    const int tid = threadIdx.x;
    const int o = tid >> 4;        // out capsule
    const int e = tid & 15;        // atom = a*4+c
    const int c = e & 3;

    const int n   = blockIdx.x;
    const int b   = n / (HO * WO);
    const int rem = n - b * (HO * WO);
    const int ho  = rem / WO;
    const int wo  = rem - ho * WO;

    // ---- W fragment straight from global (L1-cached, same for all blocks):
    //      wreg[ic][bb] = W[ic][o][bb][c] ----
    float wreg[IN_CAPS][4];
    #pragma unroll
    for (int i = 0; i < IN_CAPS; ++i)
        #pragma unroll
        for (int bb = 0; bb < 4; ++bb)
            wreg[i][bb] = Wg[((i * OUT_CAPS + o) * 4 + bb) * 4 + c];

    // ---- 3x3 patch: 9 px x 136 ch; pose stored in BOTH layouts ----
    for (int idx = tid; idx < KK * CIN; idx += 256) {
        int p  = idx / CIN;
        int cc = idx - p * CIN;
        int py = p / 3, px = p - py * 3;
        float val = x[(((b * H_IN + ho + py) * W_IN) + (wo + px)) * CIN + cc];
        int ic = cc / 17;
        int aa = cc - ic * 17;
        int k  = p * IN_CAPS + ic;
        if (aa == 16) {
            act_s[k] = val;
        } else {
            pose_s[pose_row(k) + aa] = val;
            pose_t[aa * 76 + k] = val;
        }
    }
    __syncthreads();

    // ---- r=0 coupling: softmax(0)*act = act/16 ----
    if (tid < KKIN) {
        float cv = act_s[tid] * 0.0625f;
        #pragma unroll
        for (int j = 0; j < OUT_CAPS; ++j) coup_s[j * 76 + tid] = cv;
    }
    __syncthreads();

    // fused-phase ownership: thread pair (k = tid>>1, hf = tid&1) owns
    // logits[k][hf*8+j], j=0..7, accumulated in lreg8 across rounds.
    const int kf  = tid >> 1;
    const int hf  = tid & 1;
    const int ick = kf & 7;
    float lreg8[8] = {0.f,0.f,0.f,0.f,0.f,0.f,0.f,0.f};

    const float4* cp = reinterpret_cast<const float4*>(&coup_s[o * 76]);
    const float4* pp = reinterpret_cast<const float4*>(&pose_t[e * 76]);

    float v = 0.f;
    #pragma unroll 1
    for (int r = 0; r < 3; ++r) {
        // ---- phase B: M[ic] = sum_p coup[8p+ic][o] * pose_t[e][8p+ic] ----
        float M[8] = {0.f,0.f,0.f,0.f,0.f,0.f,0.f,0.f};
        #pragma unroll
        for (int p = 0; p < KK; ++p) {
            const float4 c0 = cp[2*p], c1 = cp[2*p+1];
            const float4 p0 = pp[2*p], p1 = pp[2*p+1];
            M[0] = fmaf(c0.x, p0.x, M[0]);
            M[1] = fmaf(c0.y, p0.y, M[1]);
            M[2] = fmaf(c0.z, p0.z, M[2]);
            M[3] = fmaf(c0.w, p0.w, M[3]);
            M[4] = fmaf(c1.x, p1.x, M[4]);
            M[5] = fmaf(c1.y, p1.y, M[5]);
            M[6] = fmaf(c1.z, p1.z, M[6]);
            M[7] = fmaf(c1.w, p1.w, M[7]);
        }
        // combine: s = sum_ic sum_b wreg[ic][b] * M[ic] (b from quad lane)
        float s0 = 0.f, s1 = 0.f, s2 = 0.f, s3 = 0.f;
        #pragma unroll
        for (int ic = 0; ic < 8; ++ic) {
            s0 = fmaf(wreg[ic][0], dpp_f<0x00>(M[ic]), s0);
            s1 = fmaf(wreg[ic][1], dpp_f<0x55>(M[ic]), s1);
            s2 = fmaf(wreg[ic][2], dpp_f<0xAA>(M[ic]), s2);
            s3 = fmaf(wreg[ic][3], dpp_f<0xFF>(M[ic]), s3);
        }
        const float s = (s0 + s1) + (s2 + s3);

        // ---- phase C: squash ----
        const float sq = row_sum16(s * s);
        v = s * (sq / ((1.f + sq) * sqrtf(sq + 1e-7f)));

        if (r < 2) {
            // ---- G build from wreg via quad DPP (v is lane-local):
            //  G[ic,o,a,b] = sum_c' W[ic,o,b,c'] * v[o,a,c'] = quad_sum(wreg[ic][b]*v)
            //  lane (a,c) stores the b=c component at g_s[g_row(o,ic)+e] ----
            #pragma unroll
            for (int ic = 0; ic < 8; ++ic) {
                float g0 = quad_sum4(wreg[ic][0] * v);
                float g1 = quad_sum4(wreg[ic][1] * v);
                float g2 = quad_sum4(wreg[ic][2] * v);
                float g3 = quad_sum4(wreg[ic][3] * v);
                float g = (c == 0) ? g0 : (c == 1) ? g1 : (c == 2) ? g2 : g3;
                g_s[g_row(o, ic) + e] = g;
            }
            __syncthreads();
            // ---- FUSED phase D part2 + phase A (144 threads, 2 per k) ----
            if (tid < 2 * KKIN) {
                const float4* pk = reinterpret_cast<const float4*>(
                    &pose_s[pose_row(kf)]);
                const float4 p0 = pk[0], p1 = pk[1], p2 = pk[2], p3 = pk[3];
                float lg[8];
                #pragma unroll
                for (int j = 0; j < 8; ++j) {
                    const int oo = hf * 8 + j;
                    const float4* gp = reinterpret_cast<const float4*>(
                        &g_s[g_row(oo, ick)]);
                    const float4 g0 = gp[0], g1 = gp[1], g2 = gp[2], g3 = gp[3];
                    float d0 = p0.x*g0.x + p0.y*g0.y + p0.z*g0.z + p0.w*g0.w;
                    float d1 = p1.x*g1.x + p1.y*g1.y + p1.z*g1.z + p1.w*g1.w;
                    float d2 = p2.x*g2.x + p2.y*g2.y + p2.z*g2.z + p2.w*g2.w;
                    float d3 = p3.x*g3.x + p3.y*g3.y + p3.z*g3.z + p3.w*g3.w;
                    lreg8[j] += (d0 + d1) + (d2 + d3);
                    lg[j] = lreg8[j];
                }
                // softmax over 16 o: 8 local + pair combine via DPP xor1
                float mx = -1e30f;
                #pragma unroll
                for (int j = 0; j < 8; ++j) mx = fmaxf(mx, lg[j]);
                mx = fmaxf(mx, dpp_f<0xB1>(mx));
                float sum = 0.f;
                #pragma unroll
                for (int j = 0; j < 8; ++j) { lg[j] = __expf(lg[j] - mx); sum += lg[j]; }
                sum += dpp_f<0xB1>(sum);
                const float scale = act_s[kf] / sum;
                #pragma unroll
                for (int j = 0; j < 8; ++j)
                    coup_s[(hf * 8 + j) * 76 + kf] = lg[j] * scale;
            }
            __syncthreads();
        }
    }

    // ---- out[n][o][e], coalesced ----
    out[n * 256 + tid] = v;
}

extern "C" void kernel_launch(void* const* d_in, const int* in_sizes, int n_in,
                              void* d_out, int out_size, void* d_ws, size_t ws_size,
                              hipStream_t stream) {
    const float* x  = (const float*)d_in[0];   // [2,48,48,136] fp32
    const float* Wt = (const float*)d_in[1];   // [8,16,4,4]    fp32
    float* outp = (float*)d_out;               // [2,46,46,16,16] fp32
    capsule_routing_kernel<<<dim3(NPIX), dim3(256), 0, stream>>>(x, Wt, outp);
}

// Round 11
// 92.578 us; speedup vs baseline: 1.0948x; 1.0948x over previous
//
#include <hip/hip_runtime.h>

// ConvCapsuleLayer: B=2, 48x48, IN_CAPS=8, ATOMS=16, KER=3, OUT_CAPS=16, R=3.
// One 256-thread block per pixel (N=4232). Thread t=(o=t>>4, a=(t>>2)&3, c=t&3).
// Round-11: VALU-count reduction on the round-9 structure.
//  - phase-B combine via U-formulation + quad ALLREDUCE:
//      U[j] = sum_ic W[ic,o,c,j]*M[ic]  (16 pk_fma)
//      Z[j] = quad_allreduce(U[j]) = s(a,j); s = Z[c] (3 cndmask)
//    -> 35 instr vs 64, and only the ROW fragment wreg2 is needed.
//  - G build from wreg2 (verified r8 form): no LDS W reads; w_s deleted
//    (25.7 KB LDS). wreg2 is the only W fragment -> no spill pressure.
//  - packed fp32 (v_pk_fma_f32) for the M-loop and fused dots.

#define IN_CAPS 8
#define OUT_CAPS 16
#define KK 9
#define KKIN 72
#define BATCH 2
#define H_IN 48
#define W_IN 48
#define HO 46
#define WO 46
#define CIN 136
#define NPIX (BATCH*HO*WO)   // 4232

typedef float v2f __attribute__((ext_vector_type(2)));
typedef float v4f __attribute__((ext_vector_type(4)));

__device__ __forceinline__ v2f lo2(v4f v) { return __builtin_shufflevector(v, v, 0, 1); }
__device__ __forceinline__ v2f hi2(v4f v) { return __builtin_shufflevector(v, v, 2, 3); }
__device__ __forceinline__ v2f fma2(v2f a, v2f b, v2f c) {
    return __builtin_elementwise_fma(a, b, c);
}

template<int CTRL>
__device__ __forceinline__ float dpp_f(float x) {
    return __int_as_float(
        __builtin_amdgcn_update_dpp(0, __float_as_int(x), CTRL, 0xF, 0xF, true));
}
// sum across the 16 lanes of a DPP row (the e-group): 4 pure-VALU adds
__device__ __forceinline__ float row_sum16(float x) {
    x += dpp_f<0xB1>(x);    // quad_perm xor1
    x += dpp_f<0x4E>(x);    // quad_perm xor2
    x += dpp_f<0x124>(x);   // row_ror:4
    x += dpp_f<0x128>(x);   // row_ror:8
    return x;
}

// pose_s row start: stride 20 + skew in {0,4}; max skew delta -4 <= pad -> no
// overlap; splits the 4-way (k,k+8,k+16,k+24) bank group into 2-way (free).
__device__ __forceinline__ int pose_row(int k) {
    return k * 20 + ((k >> 3) & 1) * 4;
}
// G row start for (o, ic): stride 20 rows + 4*o skew
__device__ __forceinline__ int g_row(int o, int ic) {
    return (o * 8 + ic) * 20 + o * 4;
}

__global__ __launch_bounds__(256, 4)
void capsule_routing_kernel(const float* __restrict__ x,
                            const float* __restrict__ Wg,
                            float* __restrict__ out)
{
    __shared__ alignas(16) float pose_s[1440];             // skewed [k][atom] 5760 B
    __shared__ alignas(16) float pose_t[16 * 76];          // [a*4+b][k]      4864 B
    __shared__ float act_s[KKIN];                          //                  288 B
    __shared__ alignas(16) float g_s[2620];                // G              10480 B
    __shared__ alignas(16) float coup_s[OUT_CAPS * 76];    // [o][k]          4864 B
    // total ~25.7 KB

    const int tid = threadIdx.x;
    const int o = tid >> 4;        // out capsule
    const int e = tid & 15;        // atom = a*4+c
    const int c = e & 3;

    const int n   = blockIdx.x;
    const int b   = n / (HO * WO);
    const int rem = n - b * (HO * WO);
    const int ho  = rem / WO;
    const int wo  = rem - ho * WO;

    // ---- W row fragment from global (L1-cached, identical for all blocks):
    //      w01[ic] = (W[ic][o][c][0], W[ic][o][c][1]), w23 = ([2],[3]) ----
    v2f w01[IN_CAPS], w23[IN_CAPS];
    #pragma unroll
    for (int i = 0; i < IN_CAPS; ++i) {
        const v4f wv = *reinterpret_cast<const v4f*>(
            &Wg[((i * OUT_CAPS + o) * 4 + c) * 4]);
        w01[i] = lo2(wv);
        w23[i] = hi2(wv);
    }

    // ---- 3x3 patch: 9 px x 136 ch; pose stored in BOTH layouts ----
    for (int idx = tid; idx < KK * CIN; idx += 256) {
        int p  = idx / CIN;
        int cc = idx - p * CIN;
        int py = p / 3, px = p - py * 3;
        float val = x[(((b * H_IN + ho + py) * W_IN) + (wo + px)) * CIN + cc];
        int ic = cc / 17;
        int aa = cc - ic * 17;
        int k  = p * IN_CAPS + ic;
        if (aa == 16) {
            act_s[k] = val;
        } else {
            pose_s[pose_row(k) + aa] = val;
            pose_t[aa * 76 + k] = val;
        }
    }
    __syncthreads();

    // ---- r=0 coupling: softmax(0)*act = act/16 ----
    if (tid < KKIN) {
        float cv = act_s[tid] * 0.0625f;
        #pragma unroll
        for (int j = 0; j < OUT_CAPS; ++j) coup_s[j * 76 + tid] = cv;
    }
    __syncthreads();

    // fused-phase ownership: thread pair (k = tid>>1, hf = tid&1) owns
    // logits[k][hf*8+j], j=0..7, accumulated in lreg8 across rounds.
    const int kf  = tid >> 1;
    const int hf  = tid & 1;
    const int ick = kf & 7;
    float lreg8[8] = {0.f,0.f,0.f,0.f,0.f,0.f,0.f,0.f};

    const v4f* cp = reinterpret_cast<const v4f*>(&coup_s[o * 76]);
    const v4f* pp = reinterpret_cast<const v4f*>(&pose_t[e * 76]);

    float v = 0.f;
    #pragma unroll 1
    for (int r = 0; r < 3; ++r) {
        // ---- phase B: M[ic] = sum_p coup[8p+ic][o] * pose_t[e][8p+ic]
        //      packed: M01=(ic0,ic1), M23=(ic2,ic3), M45, M67 ----
        v2f M01 = {0.f,0.f}, M23 = {0.f,0.f}, M45 = {0.f,0.f}, M67 = {0.f,0.f};
        #pragma unroll
        for (int p = 0; p < KK; ++p) {
            const v4f c0 = cp[2*p], c1 = cp[2*p+1];
            const v4f q0 = pp[2*p], q1 = pp[2*p+1];
            M01 = fma2(lo2(c0), lo2(q0), M01);
            M23 = fma2(hi2(c0), hi2(q0), M23);
            M45 = fma2(lo2(c1), lo2(q1), M45);
            M67 = fma2(hi2(c1), hi2(q1), M67);
        }
        const float Mc[8] = {M01.x, M01.y, M23.x, M23.y,
                             M45.x, M45.y, M67.x, M67.y};
        // U[j] = sum_ic W[ic,o,c,j] * M[ic]   (16 pk_fma)
        v2f U01 = {0.f,0.f}, U23 = {0.f,0.f};
        #pragma unroll
        for (int ic = 0; ic < 8; ++ic) {
            const v2f mm = {Mc[ic], Mc[ic]};
            U01 = fma2(w01[ic], mm, U01);
            U23 = fma2(w23[ic], mm, U23);
        }
        // quad allreduce: Z[j] = sum over quad lanes b of U_b[j] = s(a, c=j)
        float Z0 = U01.x, Z1 = U01.y, Z2 = U23.x, Z3 = U23.y;
        Z0 += dpp_f<0xB1>(Z0); Z1 += dpp_f<0xB1>(Z1);
        Z2 += dpp_f<0xB1>(Z2); Z3 += dpp_f<0xB1>(Z3);
        Z0 += dpp_f<0x4E>(Z0); Z1 += dpp_f<0x4E>(Z1);
        Z2 += dpp_f<0x4E>(Z2); Z3 += dpp_f<0x4E>(Z3);
        const float s = (c == 0) ? Z0 : (c == 1) ? Z1 : (c == 2) ? Z2 : Z3;

        // ---- phase C: squash ----
        const float sq = row_sum16(s * s);
        v = s * (sq / ((1.f + sq) * sqrtf(sq + 1e-7f)));

        if (r < 2) {
            // ---- G build from wreg2 (verified r8 form):
            //  G[ic,o,a,b=c] = sum_j W[ic,o,c,j]*v(o,a,j) ----
            const float vq0 = dpp_f<0x00>(v);
            const float vq1 = dpp_f<0x55>(v);
            const float vq2 = dpp_f<0xAA>(v);
            const float vq3 = dpp_f<0xFF>(v);
            const v2f vq01 = {vq0, vq1};
            const v2f vq23 = {vq2, vq3};
            #pragma unroll
            for (int ic = 0; ic < 8; ++ic) {
                v2f h = fma2(w23[ic], vq23, w01[ic] * vq01);
                g_s[g_row(o, ic) + e] = h.x + h.y;
            }
            __syncthreads();
            // ---- FUSED phase D part2 + phase A (144 threads, 2 per k) ----
            if (tid < 2 * KKIN) {
                const v4f* pk = reinterpret_cast<const v4f*>(
                    &pose_s[pose_row(kf)]);
                const v4f p0 = pk[0], p1 = pk[1], p2 = pk[2], p3 = pk[3];
                const v2f q0 = lo2(p0), q1 = hi2(p0), q2 = lo2(p1), q3 = hi2(p1);
                const v2f q4 = lo2(p2), q5 = hi2(p2), q6 = lo2(p3), q7 = hi2(p3);
                float lg[8];
                #pragma unroll
                for (int j = 0; j < 8; ++j) {
                    const int oo = hf * 8 + j;
                    const v4f* gp = reinterpret_cast<const v4f*>(
                        &g_s[g_row(oo, ick)]);
                    const v4f g0 = gp[0], g1 = gp[1], g2 = gp[2], g3 = gp[3];
                    v2f A = fma2(q2, lo2(g1), fma2(q4, lo2(g2),
                              fma2(q6, lo2(g3), q0 * lo2(g0))));
                    v2f Bv = fma2(q3, hi2(g1), fma2(q5, hi2(g2),
                              fma2(q7, hi2(g3), q1 * hi2(g0))));
                    lreg8[j] += (A.x + A.y) + (Bv.x + Bv.y);
                    lg[j] = lreg8[j];
                }
                // softmax over 16 o: 8 local + pair combine via DPP xor1
                float mx = -1e30f;
                #pragma unroll
                for (int j = 0; j < 8; ++j) mx = fmaxf(mx, lg[j]);
                mx = fmaxf(mx, dpp_f<0xB1>(mx));
                float sum = 0.f;
                #pragma unroll
                for (int j = 0; j < 8; ++j) { lg[j] = __expf(lg[j] - mx); sum += lg[j]; }
                sum += dpp_f<0xB1>(sum);
                const float scale = act_s[kf] / sum;
                #pragma unroll
                for (int j = 0; j < 8; ++j)
                    coup_s[(hf * 8 + j) * 76 + kf] = lg[j] * scale;
            }
            __syncthreads();
        }
    }

    // ---- out[n][o][e], coalesced ----
    out[n * 256 + tid] = v;
}

extern "C" void kernel_launch(void* const* d_in, const int* in_sizes, int n_in,
                              void* d_out, int out_size, void* d_ws, size_t ws_size,
                              hipStream_t stream) {
    const float* x  = (const float*)d_in[0];   // [2,48,48,136] fp32
    const float* Wt = (const float*)d_in[1];   // [8,16,4,4]    fp32
    float* outp = (float*)d_out;               // [2,46,46,16,16] fp32
    capsule_routing_kernel<<<dim3(NPIX), dim3(256), 0, stream>>>(x, Wt, outp);
}